// Round 1
// baseline (379.480 us; speedup 1.0000x reference)
//
#include <hip/hip_runtime.h>

// 192^3 FDTD: step1 E->H (curl E), step2 H->E (curl H2), central differences
// defined only on the strict interior of ALL three dims; boundaries get zero
// curl contribution.

#define NXD 192
#define NYD 192
#define NZD 192

static constexpr int   N3      = NXD * NYD * NZD;     // 7,077,888
static constexpr float DTc     = 1e-12f;
static constexpr float INV2D   = 500.0f;              // 1/(2*1e-3), same for x,y,z

static constexpr int SX = NYD * NZD;  // x-axis stride
static constexpr int SY = NZD;        // y-axis stride

__global__ __launch_bounds__(256) void fdtd_step1(
    const float* __restrict__ Ex, const float* __restrict__ Ey, const float* __restrict__ Ez,
    const float* __restrict__ Hx, const float* __restrict__ Hy, const float* __restrict__ Hz,
    const float* __restrict__ mu,
    float* __restrict__ Hx2, float* __restrict__ Hy2, float* __restrict__ Hz2)
{
    int idx = blockIdx.x * blockDim.x + threadIdx.x;
    if (idx >= N3) return;

    int k = idx % NZD;
    int t = idx / NZD;
    int j = t % NYD;
    int i = t / NYD;

    float cx = 0.0f, cy = 0.0f, cz = 0.0f;
    if (i > 0 && i < NXD - 1 && j > 0 && j < NYD - 1 && k > 0 && k < NZD - 1) {
        float dEz_dy = (Ez[idx + SY] - Ez[idx - SY]) * INV2D;
        float dEy_dz = (Ey[idx + 1 ] - Ey[idx - 1 ]) * INV2D;
        float dEx_dz = (Ex[idx + 1 ] - Ex[idx - 1 ]) * INV2D;
        float dEz_dx = (Ez[idx + SX] - Ez[idx - SX]) * INV2D;
        float dEy_dx = (Ey[idx + SX] - Ey[idx - SX]) * INV2D;
        float dEx_dy = (Ex[idx + SY] - Ex[idx - SY]) * INV2D;
        cx = dEz_dy - dEy_dz;
        cy = dEx_dz - dEz_dx;
        cz = dEy_dx - dEx_dy;
    }

    float f = DTc / mu[idx];
    Hx2[idx] = Hx[idx] - f * cx;
    Hy2[idx] = Hy[idx] - f * cy;
    Hz2[idx] = Hz[idx] - f * cz;
}

__global__ __launch_bounds__(256) void fdtd_step2(
    const float* __restrict__ Ex, const float* __restrict__ Ey, const float* __restrict__ Ez,
    const float* __restrict__ Hx2, const float* __restrict__ Hy2, const float* __restrict__ Hz2,
    const float* __restrict__ eps, const float* __restrict__ sigma,
    float* __restrict__ Ex2, float* __restrict__ Ey2, float* __restrict__ Ez2)
{
    int idx = blockIdx.x * blockDim.x + threadIdx.x;
    if (idx >= N3) return;

    int k = idx % NZD;
    int t = idx / NZD;
    int j = t % NYD;
    int i = t / NYD;

    float cx = 0.0f, cy = 0.0f, cz = 0.0f;
    if (i > 0 && i < NXD - 1 && j > 0 && j < NYD - 1 && k > 0 && k < NZD - 1) {
        float dHz_dy = (Hz2[idx + SY] - Hz2[idx - SY]) * INV2D;
        float dHy_dz = (Hy2[idx + 1 ] - Hy2[idx - 1 ]) * INV2D;
        float dHx_dz = (Hx2[idx + 1 ] - Hx2[idx - 1 ]) * INV2D;
        float dHz_dx = (Hz2[idx + SX] - Hz2[idx - SX]) * INV2D;
        float dHy_dx = (Hy2[idx + SX] - Hy2[idx - SX]) * INV2D;
        float dHx_dy = (Hx2[idx + SY] - Hx2[idx - SY]) * INV2D;
        cx = dHz_dy - dHy_dz;
        cy = dHx_dz - dHz_dx;
        cz = dHy_dx - dHx_dy;
    }

    float e  = eps[idx];
    float s  = sigma[idx];
    float half_sdt_over_e = s * DTc / (2.0f * e);   // sig*DT/(2*eps)
    float Ap = 1.0f + half_sdt_over_e;
    float Am = 1.0f - half_sdt_over_e;
    float coefE = Am / Ap;
    float coefC = DTc / (e * Ap);

    Ex2[idx] = coefE * Ex[idx] + coefC * cx;
    Ey2[idx] = coefE * Ey[idx] + coefC * cy;
    Ez2[idx] = coefE * Ez[idx] + coefC * cz;
}

extern "C" void kernel_launch(void* const* d_in, const int* in_sizes, int n_in,
                              void* d_out, int out_size, void* d_ws, size_t ws_size,
                              hipStream_t stream)
{
    // setup_inputs order: Ex, Ey, Ez, Hx, Hy, Hz, eps, mu, sigma
    const float* Ex    = (const float*)d_in[0];
    const float* Ey    = (const float*)d_in[1];
    const float* Ez    = (const float*)d_in[2];
    const float* Hx    = (const float*)d_in[3];
    const float* Hy    = (const float*)d_in[4];
    const float* Hz    = (const float*)d_in[5];
    const float* eps   = (const float*)d_in[6];
    const float* mu    = (const float*)d_in[7];
    const float* sigma = (const float*)d_in[8];

    // outputs concatenated flat in return order: ex2, ey2, ez2, hx2, hy2, hz2
    float* out = (float*)d_out;
    float* Ex2 = out + 0 * (size_t)N3;
    float* Ey2 = out + 1 * (size_t)N3;
    float* Ez2 = out + 2 * (size_t)N3;
    float* Hx2 = out + 3 * (size_t)N3;
    float* Hy2 = out + 4 * (size_t)N3;
    float* Hz2 = out + 5 * (size_t)N3;

    const int block = 256;
    const int grid  = (N3 + block - 1) / block;  // 27648

    fdtd_step1<<<grid, block, 0, stream>>>(Ex, Ey, Ez, Hx, Hy, Hz, mu, Hx2, Hy2, Hz2);
    fdtd_step2<<<grid, block, 0, stream>>>(Ex, Ey, Ez, Hx2, Hy2, Hz2, eps, sigma, Ex2, Ey2, Ez2);
}